// Round 4
// baseline (401.172 us; speedup 1.0000x reference)
//
#include <hip/hip_runtime.h>
#include <cstdint>
#include <math.h>

typedef __attribute__((ext_vector_type(8))) __bf16 bf16x8;
typedef __attribute__((ext_vector_type(4))) float f32x4;
typedef unsigned short ushort_t;

__device__ __forceinline__ ushort_t f2bf(float f) {
    uint32_t u = __float_as_uint(f);
    u += 0x7fff + ((u >> 16) & 1);   // RNE
    return (ushort_t)(u >> 16);
}

__device__ __forceinline__ float gelu_exact(float v) {
    return 0.5f * v * (1.0f + erff(v * 0.70710678118654752440f));
}

// ---------------- weight convert (both W1 and W2 in one launch) ----------------
__global__ void convert_w2_kernel(const float* __restrict__ s1, const float* __restrict__ s2,
                                  ushort_t* __restrict__ d1, ushort_t* __restrict__ d2,
                                  int n4) {
    int i = blockIdx.x * blockDim.x + threadIdx.x;
    const float* src; ushort_t* dst; int k;
    if (i < n4) { src = s1; dst = d1; k = i; }
    else if (i < 2 * n4) { src = s2; dst = d2; k = i - n4; }
    else return;
    const float4 v = ((const float4*)src)[k];
    ushort4 o;
    o.x = f2bf(v.x); o.y = f2bf(v.y); o.z = f2bf(v.z); o.w = f2bf(v.w);
    ((ushort4*)dst)[k] = o;
}

// ---------------- token sort + device-side tile schedules ----------------
// meta: [e]=cnt  [4+e]=row off (128-aligned)  [8+e]=acnt  [12+e]=mtiles
//       [16+e]=xoff(elems)  [20+e]=hoff(elems)  [24+k]=g1 start (expert 3-k)
//       [28]=rows total  [29]=T1  [32+k]=g2 start (expert 3-k)  [36]=T2
//       [40]=queue1  [41]=queue2  [44+e]=pbuf off(floats)  [48+e]=splits s(e)
#define SORT_T 256
__global__ void sort_kernel(const int* __restrict__ tm, int M, int D, int H,
                            int* __restrict__ meta, int* __restrict__ sidx, int splitk) {
    __shared__ int lc[4][SORT_T + 1];
    __shared__ int soff[4];
    const int t = threadIdx.x;
    const int nj = M / SORT_T;
    int c0 = 0, c1 = 0, c2 = 0, c3 = 0;
    for (int j = 0; j < nj; j++) {
        int e = tm[t + j * SORT_T];          // coalesced
        c0 += (e == 0); c1 += (e == 1); c2 += (e == 2); c3 += (e == 3);
    }
    lc[0][t + 1] = c0; lc[1][t + 1] = c1; lc[2][t + 1] = c2; lc[3][t + 1] = c3;
    if (t < 4) lc[t][0] = 0;
    __syncthreads();
    if (t < 4) {   // 4 lanes scan their expert's array in lockstep
        int acc = 0;
        for (int i = 1; i <= SORT_T; i++) { acc += lc[t][i]; lc[t][i] = acc; }
    }
    __syncthreads();
    if (t == 0) {
        int off = 0, xoff = 0, hoff = 0;
        for (int e = 0; e < 4; e++) {
            int c = lc[e][SORT_T];
            int ac = (c + 127) & ~127;
            int din = D >> (3 - e), dh = H >> (3 - e);
            meta[e] = c; meta[4 + e] = off; meta[8 + e] = ac; meta[12 + e] = ac >> 7;
            meta[16 + e] = xoff; meta[20 + e] = hoff;
            soff[e] = off;
            off += ac; xoff += ac * din; hoff += ac * dh;
        }
        meta[28] = off;
        int a = 0, b = 0;
        for (int k = 0; k < 4; k++) {        // heavy expert (3) first
            int e = 3 - k;
            int Ke = H >> (3 - e);
            int s = (splitk && Ke > 1024) ? (Ke >> 10) : 1;
            meta[48 + e] = s;
            meta[24 + k] = a; a += meta[12 + e] * (Ke >> 7);
            meta[32 + k] = b; b += meta[12 + e] * (D >> 7) * s;
        }
        meta[29] = a; meta[36] = b;
        int poff = 0;
        for (int e = 0; e < 4; e++) {
            meta[44 + e] = poff;
            if (meta[48 + e] > 1) poff += meta[8 + e] * D * meta[48 + e];
        }
        meta[40] = 0; meta[41] = 0;
    }
    __syncthreads();
    int pos[4];
    pos[0] = soff[0] + lc[0][t]; pos[1] = soff[1] + lc[1][t];
    pos[2] = soff[2] + lc[2][t]; pos[3] = soff[3] + lc[3][t];
    for (int j = 0; j < nj; j++) {
        int i = t + j * SORT_T;
        int e = tm[i];
        sidx[pos[e]++] = i;
    }
    __syncthreads();
    for (int e = 0; e < 4; e++) {
        int s = soff[e] + lc[e][SORT_T];
        int n = meta[8 + e] - lc[e][SORT_T];
        for (int i = t; i < n; i += SORT_T) sidx[s + i] = -1;
    }
}

// ---------------- sorted/truncated x convert: xb compacted (stride d_in(e)) -----
__global__ void convert_x_sorted(const float* __restrict__ x,
                                 const int* __restrict__ meta,
                                 const int* __restrict__ sidx,
                                 ushort_t* __restrict__ xb, int D) {
    const int p = blockIdx.x;
    if (p >= meta[28]) return;
    const int e = (p >= meta[5]) + (p >= meta[6]) + (p >= meta[7]);
    const int off = meta[4 + e];
    const int din = D >> (3 - e);
    const int tok = sidx[p];
    ushort_t* dst = xb + (size_t)meta[16 + e] + (size_t)(p - off) * din;
    if (tok < 0) {
        for (int c = threadIdx.x * 4; c < din; c += blockDim.x * 4)
            *(ushort4*)(dst + c) = ushort4{0, 0, 0, 0};
    } else {
        const float* src = x + (size_t)tok * D;
        for (int c = threadIdx.x * 4; c < din; c += blockDim.x * 4) {
            const float4 v = *(const float4*)(src + c);
            ushort4 o;
            o.x = f2bf(v.x); o.y = f2bf(v.y); o.z = f2bf(v.z); o.w = f2bf(v.w);
            *(ushort4*)(dst + c) = o;
        }
    }
}

// ---------------- persistent GEMM, dynamic LPT work queue ----------
// EPI==0: A=xb(lda=din) B=W1(ldb=D) K=din N=dh -> h=gelu(acc+b1) bf16, ldc=dh
// EPI==1: A=hb(lda=dh)  B=W2(ldb=H) K-chunked  N=D
//         s==1: out[sidx]=acc+b2 (fp32 scatter); s>1: fp32 partial to pbuf
template <int EPI>
__global__ void gemm_sorted(const ushort_t* __restrict__ Abuf,
                            const ushort_t* __restrict__ Bw,
                            const float* __restrict__ bias,
                            const int* __restrict__ meta,
                            const int* __restrict__ sidx,
                            ushort_t* __restrict__ hb,
                            float* __restrict__ out,
                            float* __restrict__ pbuf,
                            int* __restrict__ qc,
                            int D, int H) {
    __shared__ ushort_t As[128 * 32];
    __shared__ ushort_t Bs[128 * 32];
    __shared__ int s_idx;

    const int t    = threadIdx.x;
    const int wave = t >> 6;
    const int lane = t & 63;
    const int quad = lane >> 4;
    const int l16  = lane & 15;
    const int wm   = wave & 1;
    const int wn   = wave >> 1;
    const int srow = t >> 2;
    const int scol = (t & 3) * 8;
    char* AsB = (char*)As;
    char* BsB = (char*)Bs;
    const int ldsoff = wave * 64 * 16;

    const int* st = meta + (EPI == 0 ? 24 : 32);
    const int  T  = meta[EPI == 0 ? 29 : 36];

    for (;;) {
        if (t == 0) s_idx = atomicAdd(qc, 1);
        __syncthreads();
        const int idx = s_idx;
        if (idx >= T) break;

        const int k3 = (idx >= st[1]) + (idx >= st[2]) + (idx >= st[3]);
        const int e = 3 - k3;
        const int local = idx - st[k3];
        const int mtiles = meta[12 + e];
        const int Kfull = (EPI == 0) ? (D >> (3 - e)) : (H >> (3 - e));
        int mt, nt, sk = 0, s = 1;
        if (EPI == 0) {
            mt = local % mtiles;
            nt = local / mtiles;
        } else {
            s = meta[48 + e];
            mt = local % mtiles;
            const int q = local / mtiles;
            sk = q - (q / s) * s;
            nt = q / s;
        }
        const int Kc = Kfull / s;
        const int kbeg = sk * Kc;
        const int Ne  = (EPI == 0) ? (H >> (3 - e)) : D;
        const int lda = Kfull;
        const int ldb = (EPI == 0) ? D : H;
        const int nb  = nt * 128;
        const ushort_t* A = Abuf + (size_t)((EPI == 0) ? meta[16 + e] : meta[20 + e]);

        const ushort_t* Ag = A + (size_t)(mt * 128 + srow) * lda + kbeg + scol;
        const ushort_t* Bg = Bw + (size_t)(nb + srow) * ldb + kbeg + scol;

        f32x4 acc[4][4] = {};

        for (int kt = 0; kt < Kc; kt += 32) {
            __syncthreads();
            __builtin_amdgcn_global_load_lds(
                (__attribute__((address_space(1))) void*)(uintptr_t)(Ag + kt),
                (__attribute__((address_space(3))) void*)(AsB + ldsoff), 16, 0, 0);
            __builtin_amdgcn_global_load_lds(
                (__attribute__((address_space(1))) void*)(uintptr_t)(Ag + (size_t)64 * lda + kt),
                (__attribute__((address_space(3))) void*)(AsB + 4096 + ldsoff), 16, 0, 0);
            __builtin_amdgcn_global_load_lds(
                (__attribute__((address_space(1))) void*)(uintptr_t)(Bg + kt),
                (__attribute__((address_space(3))) void*)(BsB + ldsoff), 16, 0, 0);
            __builtin_amdgcn_global_load_lds(
                (__attribute__((address_space(1))) void*)(uintptr_t)(Bg + (size_t)64 * ldb + kt),
                (__attribute__((address_space(3))) void*)(BsB + 4096 + ldsoff), 16, 0, 0);
            __syncthreads();

            bf16x8 af[4], bfr[4];
#pragma unroll
            for (int i = 0; i < 4; i++) {
                af[i]  = *(const bf16x8*)(As + (wm * 64 + i * 16 + l16) * 32 + quad * 8);
                bfr[i] = *(const bf16x8*)(Bs + (wn * 64 + i * 16 + l16) * 32 + quad * 8);
            }
#pragma unroll
            for (int i = 0; i < 4; i++)
#pragma unroll
                for (int j = 0; j < 4; j++)
                    acc[i][j] = __builtin_amdgcn_mfma_f32_16x16x32_bf16(af[i], bfr[j], acc[i][j], 0, 0, 0);
        }

        // epilogue: C/D layout col=lane&15, row=quad*4+reg
        const int colbase = nb + wn * 64 + l16;

        if (EPI == 0) {
            float bv[4];
#pragma unroll
            for (int j = 0; j < 4; j++) bv[j] = bias[colbase + j * 16];
#pragma unroll
            for (int i = 0; i < 4; i++) {
#pragma unroll
                for (int r = 0; r < 4; r++) {
                    const int lrow = mt * 128 + wm * 64 + i * 16 + quad * 4 + r;
                    ushort_t* dst = hb + (size_t)meta[20 + e] + (size_t)lrow * Ne;
#pragma unroll
                    for (int j = 0; j < 4; j++)
                        dst[colbase + j * 16] = f2bf(gelu_exact(acc[i][j][r] + bv[j]));
                }
            }
        } else if (s == 1) {
            float bv[4];
#pragma unroll
            for (int j = 0; j < 4; j++) bv[j] = bias[colbase + j * 16];
#pragma unroll
            for (int i = 0; i < 4; i++) {
#pragma unroll
                for (int r = 0; r < 4; r++) {
                    const int lrow = mt * 128 + wm * 64 + i * 16 + quad * 4 + r;
                    const int tok = sidx[meta[4 + e] + lrow];
                    if (tok >= 0) {
                        float* dst = out + (size_t)tok * D;
#pragma unroll
                        for (int j = 0; j < 4; j++)
                            dst[colbase + j * 16] = acc[i][j][r] + bv[j];
                    }
                }
            }
        } else {
            float* pb = pbuf + meta[44 + e] + (size_t)sk * meta[8 + e] * D;
#pragma unroll
            for (int i = 0; i < 4; i++) {
#pragma unroll
                for (int r = 0; r < 4; r++) {
                    const int lrow = mt * 128 + wm * 64 + i * 16 + quad * 4 + r;
                    float* dst = pb + (size_t)lrow * D;
#pragma unroll
                    for (int j = 0; j < 4; j++)
                        dst[colbase + j * 16] = acc[i][j][r];
                }
            }
        }
        __syncthreads();
    }
}

// ---------------- split-K reduction: out[tok] = b2 + sum_sk pbuf ----------------
__global__ void reduce_out(const float* __restrict__ pbuf, const float* __restrict__ b2,
                           const int* __restrict__ meta, const int* __restrict__ sidx,
                           float* __restrict__ out, int D) {
    const int p = blockIdx.x;
    if (p >= meta[28]) return;
    const int e = (p >= meta[5]) + (p >= meta[6]) + (p >= meta[7]);
    const int s = meta[48 + e];
    if (s == 1) return;
    const int tok = sidx[p];
    if (tok < 0) return;
    const int lrow = p - meta[4 + e];
    const float* src = pbuf + meta[44 + e] + (size_t)lrow * D;
    const size_t stride = (size_t)meta[8 + e] * D;
    float* dst = out + (size_t)tok * D;
    for (int c = threadIdx.x * 4; c < D; c += blockDim.x * 4) {
        float4 a = *(const float4*)(b2 + c);
        for (int k = 0; k < s; k++) {
            const float4 v = *(const float4*)(src + k * stride + c);
            a.x += v.x; a.y += v.y; a.z += v.z; a.w += v.w;
        }
        *(float4*)(dst + c) = a;
    }
}

// ---------------- fallback: naive fp32 per-token ----------------
__global__ void naive_kernel(const float* __restrict__ x, const int* __restrict__ tm,
                             const float* __restrict__ W1, const float* __restrict__ b1,
                             const float* __restrict__ W2, const float* __restrict__ b2,
                             float* __restrict__ out, int D, int Hdim) {
    const int t = blockIdx.x;
    const int m = tm[t];
    const int din = D >> (3 - m);
    const int dh = Hdim >> (3 - m);
    extern __shared__ float sm[];
    float* xs = sm;
    float* hs = sm + D;
    for (int i = threadIdx.x; i < din; i += blockDim.x) xs[i] = x[(size_t)t * D + i];
    __syncthreads();
    for (int h = threadIdx.x; h < dh; h += blockDim.x) {
        const float* w = W1 + (size_t)h * D;
        float a = b1[h];
        for (int d = 0; d < din; d++) a += xs[d] * w[d];
        hs[h] = gelu_exact(a);
    }
    __syncthreads();
    for (int d = threadIdx.x; d < D; d += blockDim.x) {
        const float* w = W2 + (size_t)d * Hdim;
        float a = b2[d];
        for (int h = 0; h < dh; h++) a += hs[h] * w[h];
        out[(size_t)t * D + d] = a;
    }
}

extern "C" void kernel_launch(void* const* d_in, const int* in_sizes, int n_in,
                              void* d_out, int out_size, void* d_ws, size_t ws_size,
                              hipStream_t stream) {
    const float* x  = (const float*)d_in[0];
    const int* tm   = (const int*)d_in[1];
    const float* W1 = (const float*)d_in[2];
    const float* b1 = (const float*)d_in[3];
    const float* W2 = (const float*)d_in[4];
    const float* b2 = (const float*)d_in[5];
    float* out = (float*)d_out;

    const int M    = in_sizes[1];
    const int Hdim = in_sizes[3];
    const int D    = in_sizes[0] / M;

    const int Mpad = M + 512;
    const size_t meta_sz = 256;
    const size_t sidx_sz = ((size_t)Mpad * 4 + 255) & ~(size_t)255;
    const size_t xb_sz   = (size_t)Mpad * D * 2;
    const size_t w1_sz   = (size_t)Hdim * D * 2;
    const size_t w2_sz   = (size_t)D * Hdim * 2;
    const size_t hb_sz   = (size_t)Mpad * Hdim * 2;
    const size_t need_sorted = meta_sz + sidx_sz + xb_sz + w1_sz + w2_sz + hb_sz;

    const int s3 = (Hdim > 1024) ? (Hdim / 1024) : 1;   // max split factor
    const size_t pbuf_sz = (size_t)Mpad * D * s3 * 4;   // worst case: all tokens expert 3
    const size_t need_split = need_sorted + pbuf_sz;

    const bool shape_ok = (M % 256 == 0) && (D % 128 == 0) && (Hdim % 128 == 0) &&
                          (D >= 1024) && (Hdim >= 4096);

    if (shape_ok && ws_size >= need_sorted) {
        const int splitk = (ws_size >= need_split) ? 1 : 0;
        char* p = (char*)d_ws;
        int* meta     = (int*)p;        p += meta_sz;
        int* sidx     = (int*)p;        p += sidx_sz;
        ushort_t* xb  = (ushort_t*)p;   p += xb_sz;
        ushort_t* w1b = (ushort_t*)p;   p += w1_sz;
        ushort_t* w2b = (ushort_t*)p;   p += w2_sz;
        ushort_t* hb  = (ushort_t*)p;   p += hb_sz;
        float* pbuf   = (float*)p;

        sort_kernel<<<1, SORT_T, 0, stream>>>(tm, M, D, Hdim, meta, sidx, splitk);
        const int n4w = Hdim * D / 4;
        convert_w2_kernel<<<(2 * n4w + 255) / 256, 256, 0, stream>>>(W1, W2, w1b, w2b, n4w);
        convert_x_sorted<<<Mpad, 64, 0, stream>>>(x, meta, sidx, xb, D);

        gemm_sorted<0><<<2048, 256, 0, stream>>>(xb, w1b, b1, meta, sidx, hb, nullptr,
                                                 pbuf, meta + 40, D, Hdim);
        gemm_sorted<1><<<2048, 256, 0, stream>>>(hb, w2b, b2, meta, sidx, nullptr, out,
                                                 pbuf, meta + 41, D, Hdim);
        if (splitk)
            reduce_out<<<Mpad, 256, 0, stream>>>(pbuf, b2, meta, sidx, out, D);
        return;
    }

    const size_t shmem = (size_t)(D + Hdim) * sizeof(float);
    naive_kernel<<<M, 256, shmem, stream>>>(x, tm, W1, b1, W2, b2, out, D, Hdim);
}

// Round 5
// 344.834 us; speedup vs baseline: 1.1634x; 1.1634x over previous
//
#include <hip/hip_runtime.h>
#include <cstdint>
#include <math.h>

typedef __attribute__((ext_vector_type(8))) __bf16 bf16x8;
typedef __attribute__((ext_vector_type(4))) float f32x4;
typedef unsigned short ushort_t;

__device__ __forceinline__ ushort_t f2bf(float f) {
    uint32_t u = __float_as_uint(f);
    u += 0x7fff + ((u >> 16) & 1);   // RNE
    return (ushort_t)(u >> 16);
}

// tanh-form gelu: max dev from exact erf-gelu ~3e-3 (<< 7e-2 threshold)
__device__ __forceinline__ float gelu_fast(float x) {
    float u = x * (0.7978845608f + 0.0356774081f * x * x);
    float e = __expf(2.0f * u);
    float th = 1.0f - 2.0f / (e + 1.0f);
    return 0.5f * x * (1.0f + th);
}

__device__ __forceinline__ float gelu_exact(float v) {
    return 0.5f * v * (1.0f + erff(v * 0.70710678118654752440f));
}

// ---------------- K_A: per-chunk expert histogram (blocks<nchunks) + W1/W2 bf16 convert ----
__global__ void histo_convw_kernel(const int* __restrict__ tm, int* __restrict__ cnt,
                                   int nchunks,
                                   const float* __restrict__ s1, const float* __restrict__ s2,
                                   ushort_t* __restrict__ d1, ushort_t* __restrict__ d2,
                                   int n4) {
    if (blockIdx.x < (unsigned)nchunks) {
        __shared__ int h[4];
        if (threadIdx.x < 4) h[threadIdx.x] = 0;
        __syncthreads();
        int e = tm[blockIdx.x * 256 + threadIdx.x];
        atomicAdd(&h[e], 1);
        __syncthreads();
        if (threadIdx.x < 4) cnt[blockIdx.x * 4 + threadIdx.x] = h[threadIdx.x];
    } else {
        const int stride = (gridDim.x - nchunks) * 256;
        for (int i = (blockIdx.x - nchunks) * 256 + threadIdx.x; i < 2 * n4; i += stride) {
            const float* src; ushort_t* dst; int k;
            if (i < n4) { src = s1; dst = d1; k = i; }
            else        { src = s2; dst = d2; k = i - n4; }
            const float4 v = ((const float4*)src)[k];
            ushort4 o;
            o.x = f2bf(v.x); o.y = f2bf(v.y); o.z = f2bf(v.z); o.w = f2bf(v.w);
            ((ushort4*)dst)[k] = o;
        }
    }
}

// ---------------- K_B: scan chunk histograms -> global chunk offsets + meta + pad fill -----
// meta: [e]=cnt  [4+e]=row off (128-aligned)  [8+e]=acnt  [12+e]=mtiles
//       [16+e]=xoff(elems)  [20+e]=hoff(elems)  [24+k]=g1 start (expert 3-k)
//       [28]=rows total  [29]=T1  [32+k]=g2 start (expert 3-k)  [36]=T2
__global__ void meta_kernel(int* __restrict__ meta, int* __restrict__ cnt,
                            int* __restrict__ sidx, int nchunks, int D, int H) {
    __shared__ int tot[4];
    __shared__ int soff_s[4];
    const int t = threadIdx.x;
    const int e = t >> 6;        // wave e handles expert e
    const int c0 = t & 63;
    int carry = 0;
    for (int base = 0; base < nchunks; base += 64) {
        int c = base + c0;
        int v = (c < nchunks) ? cnt[c * 4 + e] : 0;
        int s = v;
#pragma unroll
        for (int d = 1; d < 64; d <<= 1) {
            int y = __shfl_up(s, d);
            if (c0 >= d) s += y;
        }
        if (c < nchunks) cnt[c * 4 + e] = s - v + carry;   // expert-local exclusive
        carry += __shfl(s, 63);
    }
    if (c0 == 0) tot[e] = carry;
    __syncthreads();
    if (t == 0) {
        int off = 0, xoff = 0, hoff = 0;
        for (int ee = 0; ee < 4; ee++) {
            int c = tot[ee];
            int ac = (c + 127) & ~127;
            meta[ee] = c; meta[4 + ee] = off; meta[8 + ee] = ac; meta[12 + ee] = ac >> 7;
            meta[16 + ee] = xoff; meta[20 + ee] = hoff;
            soff_s[ee] = off;
            off += ac; xoff += ac * (D >> (3 - ee)); hoff += ac * (H >> (3 - ee));
        }
        meta[28] = off;
        int a = 0, b = 0;
        for (int k = 0; k < 4; k++) {     // heavy expert first
            int ee = 3 - k;
            meta[24 + k] = a; a += meta[12 + ee] * ((H >> (3 - ee)) >> 7);
            meta[32 + k] = b; b += meta[12 + ee] * (D >> 7);
        }
        meta[29] = a; meta[36] = b;
    }
    __syncthreads();
    for (int base = 0; base < 64 * ((nchunks + 63) / 64); base += 64) {
        int c = base + c0;
        if (c < nchunks) cnt[c * 4 + e] += soff_s[e];      // -> global start per (chunk,e)
    }
    for (int ee = 0; ee < 4; ee++) {                        // pad slots -> -1
        int s0 = soff_s[ee] + tot[ee];
        int n = meta[8 + ee] - tot[ee];
        for (int i = t; i < n; i += 256) sidx[s0 + i] = -1;
    }
}

// ---------------- K_C: stable placement via intra-chunk rank ----------------
__global__ void place_kernel(const int* __restrict__ tm, const int* __restrict__ cofs,
                             int* __restrict__ sidx) {
    __shared__ unsigned char se[256];
    const int c = blockIdx.x;
    const int t = threadIdx.x;
    const int tok = c * 256 + t;
    const int e = tm[tok];
    se[t] = (unsigned char)e;
    __syncthreads();
    int rank = 0;
    for (int i = 0; i < t; i++) rank += (se[i] == (unsigned char)e);
    sidx[cofs[c * 4 + e] + rank] = tok;
}

// ---------------- K_D: sorted/truncated x convert (compacted, stride d_in(e)) -----
__global__ void convert_x_sorted(const float* __restrict__ x,
                                 const int* __restrict__ meta,
                                 const int* __restrict__ sidx,
                                 ushort_t* __restrict__ xb, int D) {
    const int rows = meta[28];
    for (int p = blockIdx.x; p < rows; p += gridDim.x) {
        const int e = (p >= meta[5]) + (p >= meta[6]) + (p >= meta[7]);
        const int off = meta[4 + e];
        const int din = D >> (3 - e);
        const int tok = sidx[p];
        ushort_t* dst = xb + (size_t)meta[16 + e] + (size_t)(p - off) * din;
        const int c = threadIdx.x * 4;
        if (c < din) {
            if (tok < 0) {
                *(ushort4*)(dst + c) = ushort4{0, 0, 0, 0};
            } else {
                const float4 v = *(const float4*)(x + (size_t)tok * D + c);
                ushort4 o;
                o.x = f2bf(v.x); o.y = f2bf(v.y); o.z = f2bf(v.z); o.w = f2bf(v.w);
                *(ushort4*)(dst + c) = o;
            }
        }
    }
}

// ---------------- persistent per-expert GEMM, static heavy-first schedule ----------
// EPI==0: A=xb(lda=din) B=W1(ldb=D) K=din N=dh -> h=gelu(acc+b1) bf16, ldc=dh
// EPI==1: A=hb(lda=dh)  B=W2(ldb=H) K=dh  N=D -> out[sidx]=acc+b2 fp32 scatter
template <int EPI>
__global__ void gemm_sorted(const ushort_t* __restrict__ Abuf,
                            const ushort_t* __restrict__ Bw,
                            const float* __restrict__ bias,
                            const int* __restrict__ meta,
                            const int* __restrict__ sidx,
                            ushort_t* __restrict__ hb,
                            float* __restrict__ out,
                            int D, int H) {
    __shared__ ushort_t As[128 * 32];
    __shared__ ushort_t Bs[128 * 32];

    const int t    = threadIdx.x;
    const int wave = t >> 6;
    const int lane = t & 63;
    const int quad = lane >> 4;
    const int l16  = lane & 15;
    const int wm   = wave & 1;
    const int wn   = wave >> 1;
    const int srow = t >> 2;
    const int scol = (t & 3) * 8;
    char* AsB = (char*)As;
    char* BsB = (char*)Bs;
    const int ldsoff = wave * 64 * 16;

    const int* st = meta + (EPI == 0 ? 24 : 32);
    const int  T  = meta[EPI == 0 ? 29 : 36];

    for (int idx = blockIdx.x; idx < T; idx += gridDim.x) {
        const int k3 = (idx >= st[1]) + (idx >= st[2]) + (idx >= st[3]);
        const int e = 3 - k3;
        const int local = idx - st[k3];
        const int mtiles = meta[12 + e];
        const int mt = local % mtiles;
        const int nt = local / mtiles;

        const int K   = (EPI == 0) ? (D >> (3 - e)) : (H >> (3 - e));
        const int Ne  = (EPI == 0) ? (H >> (3 - e)) : D;
        const int lda = K;
        const int ldb = (EPI == 0) ? D : H;
        const int nb  = nt * 128;
        const ushort_t* A = Abuf + (size_t)((EPI == 0) ? meta[16 + e] : meta[20 + e]);

        const ushort_t* Ag = A + (size_t)(mt * 128 + srow) * lda + scol;
        const ushort_t* Bg = Bw + (size_t)(nb + srow) * ldb + scol;

        f32x4 acc[4][4] = {};

        for (int kt = 0; kt < K; kt += 32) {
            __syncthreads();
            __builtin_amdgcn_global_load_lds(
                (__attribute__((address_space(1))) void*)(uintptr_t)(Ag + kt),
                (__attribute__((address_space(3))) void*)(AsB + ldsoff), 16, 0, 0);
            __builtin_amdgcn_global_load_lds(
                (__attribute__((address_space(1))) void*)(uintptr_t)(Ag + (size_t)64 * lda + kt),
                (__attribute__((address_space(3))) void*)(AsB + 4096 + ldsoff), 16, 0, 0);
            __builtin_amdgcn_global_load_lds(
                (__attribute__((address_space(1))) void*)(uintptr_t)(Bg + kt),
                (__attribute__((address_space(3))) void*)(BsB + ldsoff), 16, 0, 0);
            __builtin_amdgcn_global_load_lds(
                (__attribute__((address_space(1))) void*)(uintptr_t)(Bg + (size_t)64 * ldb + kt),
                (__attribute__((address_space(3))) void*)(BsB + 4096 + ldsoff), 16, 0, 0);
            __syncthreads();

            bf16x8 af[4], bfr[4];
#pragma unroll
            for (int i = 0; i < 4; i++) {
                af[i]  = *(const bf16x8*)(As + (wm * 64 + i * 16 + l16) * 32 + quad * 8);
                bfr[i] = *(const bf16x8*)(Bs + (wn * 64 + i * 16 + l16) * 32 + quad * 8);
            }
#pragma unroll
            for (int i = 0; i < 4; i++)
#pragma unroll
                for (int j = 0; j < 4; j++)
                    acc[i][j] = __builtin_amdgcn_mfma_f32_16x16x32_bf16(af[i], bfr[j], acc[i][j], 0, 0, 0);
        }

        // epilogue: C/D layout col=lane&15, row=quad*4+reg
        const int colbase = nb + wn * 64 + l16;
        float bv[4];
#pragma unroll
        for (int j = 0; j < 4; j++) bv[j] = bias[colbase + j * 16];

#pragma unroll
        for (int i = 0; i < 4; i++) {
#pragma unroll
            for (int r = 0; r < 4; r++) {
                const int lrow = mt * 128 + wm * 64 + i * 16 + quad * 4 + r;
                if (EPI == 0) {
                    ushort_t* dst = hb + (size_t)meta[20 + e] + (size_t)lrow * Ne;
#pragma unroll
                    for (int j = 0; j < 4; j++)
                        dst[colbase + j * 16] = f2bf(gelu_fast(acc[i][j][r] + bv[j]));
                } else {
                    const int tok = sidx[meta[4 + e] + lrow];
                    if (tok >= 0) {
                        float* dst = out + (size_t)tok * D;
#pragma unroll
                        for (int j = 0; j < 4; j++)
                            dst[colbase + j * 16] = acc[i][j][r] + bv[j];
                    }
                }
            }
        }
    }
}

// ---------------- fallback: naive fp32 per-token ----------------
__global__ void naive_kernel(const float* __restrict__ x, const int* __restrict__ tm,
                             const float* __restrict__ W1, const float* __restrict__ b1,
                             const float* __restrict__ W2, const float* __restrict__ b2,
                             float* __restrict__ out, int D, int Hdim) {
    const int t = blockIdx.x;
    const int m = tm[t];
    const int din = D >> (3 - m);
    const int dh = Hdim >> (3 - m);
    extern __shared__ float sm[];
    float* xs = sm;
    float* hs = sm + D;
    for (int i = threadIdx.x; i < din; i += blockDim.x) xs[i] = x[(size_t)t * D + i];
    __syncthreads();
    for (int h = threadIdx.x; h < dh; h += blockDim.x) {
        const float* w = W1 + (size_t)h * D;
        float a = b1[h];
        for (int d = 0; d < din; d++) a += xs[d] * w[d];
        hs[h] = gelu_exact(a);
    }
    __syncthreads();
    for (int d = threadIdx.x; d < D; d += blockDim.x) {
        const float* w = W2 + (size_t)d * Hdim;
        float a = b2[d];
        for (int h = 0; h < dh; h++) a += hs[h] * w[h];
        out[(size_t)t * D + d] = a;
    }
}

extern "C" void kernel_launch(void* const* d_in, const int* in_sizes, int n_in,
                              void* d_out, int out_size, void* d_ws, size_t ws_size,
                              hipStream_t stream) {
    const float* x  = (const float*)d_in[0];
    const int* tm   = (const int*)d_in[1];
    const float* W1 = (const float*)d_in[2];
    const float* b1 = (const float*)d_in[3];
    const float* W2 = (const float*)d_in[4];
    const float* b2 = (const float*)d_in[5];
    float* out = (float*)d_out;

    const int M    = in_sizes[1];
    const int Hdim = in_sizes[3];
    const int D    = in_sizes[0] / M;

    const int Mpad = M + 512;
    const int nchunks = M / 256;
    const size_t meta_sz = 256;
    const size_t cnt_sz  = ((size_t)nchunks * 4 * 4 + 255) & ~(size_t)255;
    const size_t sidx_sz = ((size_t)Mpad * 4 + 255) & ~(size_t)255;
    const size_t xb_sz   = (size_t)Mpad * D * 2;
    const size_t w1_sz   = (size_t)Hdim * D * 2;
    const size_t w2_sz   = (size_t)D * Hdim * 2;
    const size_t hb_sz   = (size_t)Mpad * Hdim * 2;
    const size_t need_sorted = meta_sz + cnt_sz + sidx_sz + xb_sz + w1_sz + w2_sz + hb_sz;

    const bool shape_ok = (M % 256 == 0) && (D % 128 == 0) && (Hdim % 128 == 0) &&
                          (D >= 1024) && (D <= 1024) && (Hdim >= 4096);

    if (shape_ok && ws_size >= need_sorted) {
        char* p = (char*)d_ws;
        int* meta     = (int*)p;        p += meta_sz;
        int* cnt      = (int*)p;        p += cnt_sz;
        int* sidx     = (int*)p;        p += sidx_sz;
        ushort_t* xb  = (ushort_t*)p;   p += xb_sz;
        ushort_t* w1b = (ushort_t*)p;   p += w1_sz;
        ushort_t* w2b = (ushort_t*)p;   p += w2_sz;
        ushort_t* hb  = (ushort_t*)p;

        const int n4w = Hdim * D / 4;
        histo_convw_kernel<<<nchunks + 2048, 256, 0, stream>>>(tm, cnt, nchunks,
                                                               W1, W2, w1b, w2b, n4w);
        meta_kernel<<<1, 256, 0, stream>>>(meta, cnt, sidx, nchunks, D, Hdim);
        place_kernel<<<nchunks, 256, 0, stream>>>(tm, cnt, sidx);
        convert_x_sorted<<<2048, 256, 0, stream>>>(x, meta, sidx, xb, D);

        gemm_sorted<0><<<2048, 256, 0, stream>>>(xb, w1b, b1, meta, sidx, hb, nullptr, D, Hdim);
        gemm_sorted<1><<<2048, 256, 0, stream>>>(hb, w2b, b2, meta, sidx, nullptr, out, D, Hdim);
        return;
    }

    const size_t shmem = (size_t)(D + Hdim) * sizeof(float);
    naive_kernel<<<M, 256, shmem, stream>>>(x, tm, W1, b1, W2, b2, out, D, Hdim);
}